// Round 6
// baseline (376.116 us; speedup 1.0000x reference)
//
#include <hip/hip_runtime.h>
#include <cstdint>

// NeuralRadiance via bf16 MFMA (16x16x32), register-only inter-layer transforms.
//   L1 (transposed): h1^T = W1^T @ x^T   -- b1 folded as x[k=19]=1.0
//   L2 (transposed): h2^T = W2^T @ h1^T  -- b2 via MFMA C operand
//   L3 (normal)    : h3   = h2  @ W3     -- b3 via MFMA C operand
// Fragment facts (HW-verified per guide):
//   A-frag: lane holds A[m=lane&15][k=quad*8+j], 8 bf16
//   B-frag: lane holds B[k=quad*8+j][n=lane&15], 8 bf16
//   C/D   : lane reg r holds D[m=quad*4+r][n=lane&15], 4 f32
// Round 6: round-5 kernel unchanged except occupancy: launch_bounds(256,8)
// (VGPR cap 64; r5 measured 60) + grid 2048 -> 8 blocks/CU, LDS 8*20480 =
// exactly 160 KiB/CU, 32 waves/CU. r5 was latency-bound at 31% occupancy
// (MfmaUtil 17%, VALUBusy 52%, pipe floor ~14.5 us vs 68 us measured).

typedef short  bf16x8 __attribute__((ext_vector_type(8)));
typedef float  f32x4  __attribute__((ext_vector_type(4)));

#define MFMA16(A, B, C) __builtin_amdgcn_mfma_f32_16x16x32_bf16((A), (B), (C), 0, 0, 0)

// guaranteed-HW packed cvt: 2 f32 -> dword of 2 bf16 (lo=a, hi=b), RNE
__device__ inline int pk(float a, float b) {
    int d;
    __asm__("v_cvt_pk_bf16_f32 %0, %1, %2" : "=v"(d) : "v"(a), "v"(b));
    return d;
}
// scalar fallback for cold weight staging
__device__ inline uint32_t f2b_u(float f) {
    union { float f; uint32_t u; } x; x.f = f;
    return (x.u + 0x7FFFu + ((x.u >> 16) & 1u)) >> 16;
}
__device__ inline short f2b(float f) { return (short)f2b_u(f); }

// gfx950 lane-transpose primitives (both operands read-write)
__device__ inline void pl32_swap(int& a, int& b) {
    __asm__ volatile("v_permlane32_swap_b32 %0, %1" : "+v"(a), "+v"(b));
}
__device__ inline void pl16_swap(int& a, int& b) {
    __asm__ volatile("v_permlane16_swap_b32 %0, %1" : "+v"(a), "+v"(b));
}

// compile-time ordering only (DS pipe is in-order per wave; validated r4)
__device__ inline void cfence() { __asm__ volatile("" ::: "memory"); }

__device__ inline float sigmoid_fast(float x) {
    float e = __expf(-x);
    return __builtin_amdgcn_rcpf(1.0f + e);
}

// C/D accs (4x f32x4) -> two frag halves (int4 of bf16 pairs), with relu.
__device__ inline void cd_to_frag(const f32x4 acc[4], int4& lo, int4& hi) {
    int P0 = pk(fmaxf(acc[0][0],0.f), fmaxf(acc[0][1],0.f));
    int P1 = pk(fmaxf(acc[0][2],0.f), fmaxf(acc[0][3],0.f));
    int P2 = pk(fmaxf(acc[1][0],0.f), fmaxf(acc[1][1],0.f));
    int P3 = pk(fmaxf(acc[1][2],0.f), fmaxf(acc[1][3],0.f));
    int P4 = pk(fmaxf(acc[2][0],0.f), fmaxf(acc[2][1],0.f));
    int P5 = pk(fmaxf(acc[2][2],0.f), fmaxf(acc[2][3],0.f));
    int P6 = pk(fmaxf(acc[3][0],0.f), fmaxf(acc[3][1],0.f));
    int P7 = pk(fmaxf(acc[3][2],0.f), fmaxf(acc[3][3],0.f));
    pl32_swap(P0, P2); pl16_swap(P0, P2);   // -> T0, T2
    pl32_swap(P1, P3); pl16_swap(P1, P3);   // -> T1, T3
    pl32_swap(P4, P6); pl16_swap(P4, P6);   // -> T4, T6
    pl32_swap(P5, P7); pl16_swap(P5, P7);   // -> T5, T7
    lo = make_int4(P0, P1, P2, P3);
    hi = make_int4(P4, P5, P6, P7);
}

__device__ inline bf16x8 as_frag(int4 v) {
    bf16x8 f; __builtin_memcpy(&f, &v, sizeof(f)); return f;
}

#define XS 40   // xbuf row stride in shorts (20 dwords; b128 at bank floor)

__global__ __launch_bounds__(256, 8) void nrad_mfma_kernel(
    const float* __restrict__ pos, const float* __restrict__ nrm,
    const float* __restrict__ emb,
    const float* __restrict__ W1, const float* __restrict__ b1,
    const float* __restrict__ W2, const float* __restrict__ b2,
    const float* __restrict__ W3, const float* __restrict__ b3,
    float* __restrict__ out, int ntiles)
{
    // Arena, two barrier-separated lifetimes:
    //  phase 1: w1t@0 (4KB) w2t@4096 (8KB) w3t@12288 (384B) b2s@12672 b3s@12928
    //  phase 2: xbuf = arena + wave*5120 (64 rows x XS shorts)
    __shared__ alignas(16) char arena[20480];
    short* w1t = (short*)arena;             // [n][k] stride 32: k<19=W1, k==19=b1
    short* w2t = (short*)(arena + 4096);    // [n][k] stride 64
    short* w3t = (short*)(arena + 12288);   // [c][k] stride 64
    float* b2s = (float*)(arena + 12672);
    float* b3s = (float*)(arena + 12928);

    const int tid  = threadIdx.x;
    const int wave = tid >> 6;
    const int lane = tid & 63;
    const int q    = lane >> 4;
    const int nn   = lane & 15;

    // ---- one-time: stage transposed bf16 weights into LDS
    for (int e = tid; e < 64 * 32; e += 256) {
        int n = e >> 5, k = e & 31;
        float v = (k < 19) ? W1[k * 64 + n] : (k == 19 ? b1[n] : 0.0f);
        w1t[n * 32 + k] = f2b(v);
    }
    for (int e = tid; e < 4096; e += 256) {
        int k = e >> 6, n = e & 63;
        w2t[n * 64 + k] = f2b(W2[e]);
    }
    for (int e = tid; e < 192; e += 256) {
        int k = e / 3, c = e - k * 3;
        w3t[c * 64 + k] = f2b(W3[e]);
    }
    for (int e = tid; e < 64; e += 256) b2s[e] = b2[e];
    if (tid < 4) b3s[tid] = (tid < 3) ? b3[tid] : 0.0f;
    __syncthreads();

    // ---- per-lane register fragments (persistent across tiles)
    bf16x8 w1f[4], w2f[4][2], w3f[2];
    #pragma unroll
    for (int t = 0; t < 4; ++t)
        w1f[t] = *(const bf16x8*)(w1t + (t * 16 + nn) * 32 + q * 8);
    #pragma unroll
    for (int t = 0; t < 4; ++t)
        #pragma unroll
        for (int ks = 0; ks < 2; ++ks)
            w2f[t][ks] = *(const bf16x8*)(w2t + (t * 16 + nn) * 64 + ks * 32 + q * 8);
    {
        int c3 = (nn < 3) ? nn : 0;
        w3f[0] = *(const bf16x8*)(w3t + c3 * 64 + q * 8);
        w3f[1] = *(const bf16x8*)(w3t + c3 * 64 + 32 + q * 8);
    }
    f32x4 b2rv[4];
    #pragma unroll
    for (int t = 0; t < 4; ++t)
        b2rv[t] = *(const f32x4*)(b2s + t * 16 + q * 4);
    const float b3r = (nn < 3) ? b3s[nn] : 0.0f;
    __syncthreads();   // weights consumed into regs; arena now reusable

    short* xw = (short*)(arena + wave * 5120);   // row stride XS shorts

    const int xro  = nn * XS + q * 8;    // + sub*16*XS : L1 B-frag read
    const int oofs = q * 12 + nn;        // out: (q*4+r)*3+nn, r via stride 3

    const int wave_gid = blockIdx.x * 4 + wave;
    const int nwaves   = gridDim.x * 4;
    const float4* emb4 = (const float4*)emb;

    for (int tile = wave_gid; tile < ntiles; tile += nwaves) {
        const int base = tile * 64;
        const int i    = base + lane;

        // ---- load + hash + gather this lane's point
        const float* pp = pos + 3 * i;
        const float* np = nrm + 3 * i;
        float p0 = pp[0], p1 = pp[1], p2 = pp[2];
        float n0 = np[0], n1 = np[1], n2 = np[2];
        int s0 = (int)(p0 * 8.0f), s1 = (int)(p1 * 8.0f), s2 = (int)(p2 * 8.0f);
        uint32_t h = ((uint32_t)s0 * 73856093u) ^ ((uint32_t)s1 * 19349663u) ^
                     ((uint32_t)s2 * 83492791u);
        uint32_t idx = h & 32767u;
        float4 f0 = emb4[idx*4+0], f1 = emb4[idx*4+1];
        float4 f2 = emb4[idx*4+2], f3 = emb4[idx*4+3];

        // ---- pack into xbuf row = lane (k-major, 32 shorts + 8 pad)
        int4 A = make_int4(pk(f0.x, f0.y), pk(f0.z, f0.w), pk(f1.x, f1.y), pk(f1.z, f1.w));
        int4 B = make_int4(pk(f2.x, f2.y), pk(f2.z, f2.w), pk(f3.x, f3.y), pk(f3.z, f3.w));
        int4 C = make_int4(pk(n0, n1), pk(n2, 1.0f), 0, 0);  // k=19 -> 1.0 (bias row)
        int4 D = make_int4(0, 0, 0, 0);
        int4* xr = (int4*)(xw + lane * XS);
        xr[0] = A; xr[1] = B; xr[2] = C; xr[3] = D;
        cfence();

        const float* ob = out + (size_t)base * 3;

        #pragma unroll
        for (int sub = 0; sub < 4; ++sub) {
            // ---- L1: h1^T = W1^T @ x^T (the only LDS read per sub)
            bf16x8 xf = *(const bf16x8*)(xw + sub * 16 * XS + xro);
            f32x4 acc1[4];
            #pragma unroll
            for (int t = 0; t < 4; ++t) {
                f32x4 z = {0.0f, 0.0f, 0.0f, 0.0f};
                acc1[t] = MFMA16(w1f[t], xf, z);
            }

            // ---- relu + pack + register transpose -> h1^T B-frags
            int4 h1lo, h1hi;
            cd_to_frag(acc1, h1lo, h1hi);
            bf16x8 h1f0 = as_frag(h1lo), h1f1 = as_frag(h1hi);

            // ---- L2: h2^T = W2^T @ h1^T
            f32x4 acc2[4];
            #pragma unroll
            for (int t = 0; t < 4; ++t) {
                f32x4 c2 = MFMA16(w2f[t][0], h1f0, b2rv[t]);
                acc2[t]  = MFMA16(w2f[t][1], h1f1, c2);
            }

            // ---- relu + pack + register transpose -> h2 A-frags
            int4 h2lo, h2hi;
            cd_to_frag(acc2, h2lo, h2hi);
            bf16x8 h2f0 = as_frag(h2lo), h2f1 = as_frag(h2hi);

            // ---- L3: h3 = h2 @ W3
            f32x4 cb = {b3r, b3r, b3r, b3r};
            f32x4 c3a = MFMA16(h2f0, w3f[0], cb);
            f32x4 acc3 = MFMA16(h2f1, w3f[1], c3a);

            // ---- sigmoid + store: lane (q, nn<3), reg r -> out[pt][nn]
            float o0 = sigmoid_fast(acc3[0]);
            float o1 = sigmoid_fast(acc3[1]);
            float o2 = sigmoid_fast(acc3[2]);
            float o3 = sigmoid_fast(acc3[3]);
            if (nn < 3) {
                float* o = (float*)(ob + sub * 48 + oofs);
                o[0] = o0; o[3] = o1; o[6] = o2; o[9] = o3;
            }
        }
        cfence();   // next tile's xbuf writes stay behind this tile's reads
    }
}

extern "C" void kernel_launch(void* const* d_in, const int* in_sizes, int n_in,
                              void* d_out, int out_size, void* d_ws, size_t ws_size,
                              hipStream_t stream) {
    const float* pos = (const float*)d_in[0];
    const float* nrm = (const float*)d_in[1];
    const float* emb = (const float*)d_in[2];
    const float* W1  = (const float*)d_in[3];
    const float* b1  = (const float*)d_in[4];
    const float* W2  = (const float*)d_in[5];
    const float* b2  = (const float*)d_in[6];
    const float* W3  = (const float*)d_in[7];
    const float* b3  = (const float*)d_in[8];
    float* out = (float*)d_out;

    int n = in_sizes[0] / 3;      // 2,097,152
    int ntiles = n / 64;          // 32768
    int grid = 2048;              // 8192 waves -> exactly 4 tiles each; 8 blocks/CU
    nrad_mfma_kernel<<<grid, 256, 0, stream>>>(pos, nrm, emb, W1, b1, W2, b2,
                                               W3, b3, out, ntiles);
}

// Round 7
// 156.099 us; speedup vs baseline: 2.4095x; 2.4095x over previous
//
#include <hip/hip_runtime.h>
#include <cstdint>

// NeuralRadiance via bf16 MFMA (16x16x32), register-only inter-layer transforms.
//   L1 (transposed): h1^T = W1^T @ x^T   -- b1 folded as x[k=19]=1.0
//   L2 (transposed): h2^T = W2^T @ h1^T  -- b2 via MFMA C operand
//   L3 (normal)    : h3   = h2  @ W3     -- b3 via MFMA C operand
// Fragment facts (HW-verified per guide):
//   A-frag: lane holds A[m=lane&15][k=quad*8+j], 8 bf16
//   B-frag: lane holds B[k=quad*8+j][n=lane&15], 8 bf16
//   C/D   : lane reg r holds D[m=quad*4+r][n=lane&15], 4 f32
// Round 7: round-5 kernel EXACTLY (launch_bounds(256,4): compiler picks 60
// VGPR <= 64 -> HW allows 32 waves/CU), grid 1024 -> 2048 so 8 blocks/CU
// actually arrive (LDS 8*20480 B = exactly 160 KiB/CU). Round 6's (256,8)
// bound clamped VGPRs to 32 and spilled the weight fragments (FETCH 32->800MB)
// -- the occupancy lever is the grid, not the launch bound.

typedef short  bf16x8 __attribute__((ext_vector_type(8)));
typedef float  f32x4  __attribute__((ext_vector_type(4)));

#define MFMA16(A, B, C) __builtin_amdgcn_mfma_f32_16x16x32_bf16((A), (B), (C), 0, 0, 0)

// guaranteed-HW packed cvt: 2 f32 -> dword of 2 bf16 (lo=a, hi=b), RNE
__device__ inline int pk(float a, float b) {
    int d;
    __asm__("v_cvt_pk_bf16_f32 %0, %1, %2" : "=v"(d) : "v"(a), "v"(b));
    return d;
}
// scalar fallback for cold weight staging
__device__ inline uint32_t f2b_u(float f) {
    union { float f; uint32_t u; } x; x.f = f;
    return (x.u + 0x7FFFu + ((x.u >> 16) & 1u)) >> 16;
}
__device__ inline short f2b(float f) { return (short)f2b_u(f); }

// gfx950 lane-transpose primitives (both operands read-write)
__device__ inline void pl32_swap(int& a, int& b) {
    __asm__ volatile("v_permlane32_swap_b32 %0, %1" : "+v"(a), "+v"(b));
}
__device__ inline void pl16_swap(int& a, int& b) {
    __asm__ volatile("v_permlane16_swap_b32 %0, %1" : "+v"(a), "+v"(b));
}

// compile-time ordering only (DS pipe is in-order per wave; validated r4)
__device__ inline void cfence() { __asm__ volatile("" ::: "memory"); }

__device__ inline float sigmoid_fast(float x) {
    float e = __expf(-x);
    return __builtin_amdgcn_rcpf(1.0f + e);
}

// C/D accs (4x f32x4) -> two frag halves (int4 of bf16 pairs), with relu.
__device__ inline void cd_to_frag(const f32x4 acc[4], int4& lo, int4& hi) {
    int P0 = pk(fmaxf(acc[0][0],0.f), fmaxf(acc[0][1],0.f));
    int P1 = pk(fmaxf(acc[0][2],0.f), fmaxf(acc[0][3],0.f));
    int P2 = pk(fmaxf(acc[1][0],0.f), fmaxf(acc[1][1],0.f));
    int P3 = pk(fmaxf(acc[1][2],0.f), fmaxf(acc[1][3],0.f));
    int P4 = pk(fmaxf(acc[2][0],0.f), fmaxf(acc[2][1],0.f));
    int P5 = pk(fmaxf(acc[2][2],0.f), fmaxf(acc[2][3],0.f));
    int P6 = pk(fmaxf(acc[3][0],0.f), fmaxf(acc[3][1],0.f));
    int P7 = pk(fmaxf(acc[3][2],0.f), fmaxf(acc[3][3],0.f));
    pl32_swap(P0, P2); pl16_swap(P0, P2);   // -> T0, T2
    pl32_swap(P1, P3); pl16_swap(P1, P3);   // -> T1, T3
    pl32_swap(P4, P6); pl16_swap(P4, P6);   // -> T4, T6
    pl32_swap(P5, P7); pl16_swap(P5, P7);   // -> T5, T7
    lo = make_int4(P0, P1, P2, P3);
    hi = make_int4(P4, P5, P6, P7);
}

__device__ inline bf16x8 as_frag(int4 v) {
    bf16x8 f; __builtin_memcpy(&f, &v, sizeof(f)); return f;
}

#define XS 40   // xbuf row stride in shorts (20 dwords; b128 at bank floor)

__global__ __launch_bounds__(256, 4) void nrad_mfma_kernel(
    const float* __restrict__ pos, const float* __restrict__ nrm,
    const float* __restrict__ emb,
    const float* __restrict__ W1, const float* __restrict__ b1,
    const float* __restrict__ W2, const float* __restrict__ b2,
    const float* __restrict__ W3, const float* __restrict__ b3,
    float* __restrict__ out, int ntiles)
{
    // Arena, two barrier-separated lifetimes:
    //  phase 1: w1t@0 (4KB) w2t@4096 (8KB) w3t@12288 (384B) b2s@12672 b3s@12928
    //  phase 2: xbuf = arena + wave*5120 (64 rows x XS shorts)
    __shared__ alignas(16) char arena[20480];
    short* w1t = (short*)arena;             // [n][k] stride 32: k<19=W1, k==19=b1
    short* w2t = (short*)(arena + 4096);    // [n][k] stride 64
    short* w3t = (short*)(arena + 12288);   // [c][k] stride 64
    float* b2s = (float*)(arena + 12672);
    float* b3s = (float*)(arena + 12928);

    const int tid  = threadIdx.x;
    const int wave = tid >> 6;
    const int lane = tid & 63;
    const int q    = lane >> 4;
    const int nn   = lane & 15;

    // ---- one-time: stage transposed bf16 weights into LDS
    for (int e = tid; e < 64 * 32; e += 256) {
        int n = e >> 5, k = e & 31;
        float v = (k < 19) ? W1[k * 64 + n] : (k == 19 ? b1[n] : 0.0f);
        w1t[n * 32 + k] = f2b(v);
    }
    for (int e = tid; e < 4096; e += 256) {
        int k = e >> 6, n = e & 63;
        w2t[n * 64 + k] = f2b(W2[e]);
    }
    for (int e = tid; e < 192; e += 256) {
        int k = e / 3, c = e - k * 3;
        w3t[c * 64 + k] = f2b(W3[e]);
    }
    for (int e = tid; e < 64; e += 256) b2s[e] = b2[e];
    if (tid < 4) b3s[tid] = (tid < 3) ? b3[tid] : 0.0f;
    __syncthreads();

    // ---- per-lane register fragments (persistent across tiles)
    bf16x8 w1f[4], w2f[4][2], w3f[2];
    #pragma unroll
    for (int t = 0; t < 4; ++t)
        w1f[t] = *(const bf16x8*)(w1t + (t * 16 + nn) * 32 + q * 8);
    #pragma unroll
    for (int t = 0; t < 4; ++t)
        #pragma unroll
        for (int ks = 0; ks < 2; ++ks)
            w2f[t][ks] = *(const bf16x8*)(w2t + (t * 16 + nn) * 64 + ks * 32 + q * 8);
    {
        int c3 = (nn < 3) ? nn : 0;
        w3f[0] = *(const bf16x8*)(w3t + c3 * 64 + q * 8);
        w3f[1] = *(const bf16x8*)(w3t + c3 * 64 + 32 + q * 8);
    }
    f32x4 b2rv[4];
    #pragma unroll
    for (int t = 0; t < 4; ++t)
        b2rv[t] = *(const f32x4*)(b2s + t * 16 + q * 4);
    const float b3r = (nn < 3) ? b3s[nn] : 0.0f;
    __syncthreads();   // weights consumed into regs; arena now reusable

    short* xw = (short*)(arena + wave * 5120);   // row stride XS shorts

    const int xro  = nn * XS + q * 8;    // + sub*16*XS : L1 B-frag read
    const int oofs = q * 12 + nn;        // out: (q*4+r)*3+nn, r via stride 3

    const int wave_gid = blockIdx.x * 4 + wave;
    const int nwaves   = gridDim.x * 4;
    const float4* emb4 = (const float4*)emb;

    for (int tile = wave_gid; tile < ntiles; tile += nwaves) {
        const int base = tile * 64;
        const int i    = base + lane;

        // ---- load + hash + gather this lane's point
        const float* pp = pos + 3 * i;
        const float* np = nrm + 3 * i;
        float p0 = pp[0], p1 = pp[1], p2 = pp[2];
        float n0 = np[0], n1 = np[1], n2 = np[2];
        int s0 = (int)(p0 * 8.0f), s1 = (int)(p1 * 8.0f), s2 = (int)(p2 * 8.0f);
        uint32_t h = ((uint32_t)s0 * 73856093u) ^ ((uint32_t)s1 * 19349663u) ^
                     ((uint32_t)s2 * 83492791u);
        uint32_t idx = h & 32767u;
        float4 f0 = emb4[idx*4+0], f1 = emb4[idx*4+1];
        float4 f2 = emb4[idx*4+2], f3 = emb4[idx*4+3];

        // ---- pack into xbuf row = lane (k-major, 32 shorts + 8 pad)
        int4 A = make_int4(pk(f0.x, f0.y), pk(f0.z, f0.w), pk(f1.x, f1.y), pk(f1.z, f1.w));
        int4 B = make_int4(pk(f2.x, f2.y), pk(f2.z, f2.w), pk(f3.x, f3.y), pk(f3.z, f3.w));
        int4 C = make_int4(pk(n0, n1), pk(n2, 1.0f), 0, 0);  // k=19 -> 1.0 (bias row)
        int4 D = make_int4(0, 0, 0, 0);
        int4* xr = (int4*)(xw + lane * XS);
        xr[0] = A; xr[1] = B; xr[2] = C; xr[3] = D;
        cfence();

        const float* ob = out + (size_t)base * 3;

        #pragma unroll
        for (int sub = 0; sub < 4; ++sub) {
            // ---- L1: h1^T = W1^T @ x^T (the only LDS read per sub)
            bf16x8 xf = *(const bf16x8*)(xw + sub * 16 * XS + xro);
            f32x4 acc1[4];
            #pragma unroll
            for (int t = 0; t < 4; ++t) {
                f32x4 z = {0.0f, 0.0f, 0.0f, 0.0f};
                acc1[t] = MFMA16(w1f[t], xf, z);
            }

            // ---- relu + pack + register transpose -> h1^T B-frags
            int4 h1lo, h1hi;
            cd_to_frag(acc1, h1lo, h1hi);
            bf16x8 h1f0 = as_frag(h1lo), h1f1 = as_frag(h1hi);

            // ---- L2: h2^T = W2^T @ h1^T
            f32x4 acc2[4];
            #pragma unroll
            for (int t = 0; t < 4; ++t) {
                f32x4 c2 = MFMA16(w2f[t][0], h1f0, b2rv[t]);
                acc2[t]  = MFMA16(w2f[t][1], h1f1, c2);
            }

            // ---- relu + pack + register transpose -> h2 A-frags
            int4 h2lo, h2hi;
            cd_to_frag(acc2, h2lo, h2hi);
            bf16x8 h2f0 = as_frag(h2lo), h2f1 = as_frag(h2hi);

            // ---- L3: h3 = h2 @ W3
            f32x4 cb = {b3r, b3r, b3r, b3r};
            f32x4 c3a = MFMA16(h2f0, w3f[0], cb);
            f32x4 acc3 = MFMA16(h2f1, w3f[1], c3a);

            // ---- sigmoid + store: lane (q, nn<3), reg r -> out[pt][nn]
            float o0 = sigmoid_fast(acc3[0]);
            float o1 = sigmoid_fast(acc3[1]);
            float o2 = sigmoid_fast(acc3[2]);
            float o3 = sigmoid_fast(acc3[3]);
            if (nn < 3) {
                float* o = (float*)(ob + sub * 48 + oofs);
                o[0] = o0; o[3] = o1; o[6] = o2; o[9] = o3;
            }
        }
        cfence();   // next tile's xbuf writes stay behind this tile's reads
    }
}

extern "C" void kernel_launch(void* const* d_in, const int* in_sizes, int n_in,
                              void* d_out, int out_size, void* d_ws, size_t ws_size,
                              hipStream_t stream) {
    const float* pos = (const float*)d_in[0];
    const float* nrm = (const float*)d_in[1];
    const float* emb = (const float*)d_in[2];
    const float* W1  = (const float*)d_in[3];
    const float* b1  = (const float*)d_in[4];
    const float* W2  = (const float*)d_in[5];
    const float* b2  = (const float*)d_in[6];
    const float* W3  = (const float*)d_in[7];
    const float* b3  = (const float*)d_in[8];
    float* out = (float*)d_out;

    int n = in_sizes[0] / 3;      // 2,097,152
    int ntiles = n / 64;          // 32768
    int grid = 2048;              // 8 blocks/CU (LDS-exact), 4 tiles/wave
    nrad_mfma_kernel<<<grid, 256, 0, stream>>>(pos, nrm, emb, W1, b1, W2, b2,
                                               W3, b3, out, ntiles);
}

// Round 8
// 148.890 us; speedup vs baseline: 2.5261x; 1.0484x over previous
//
#include <hip/hip_runtime.h>
#include <cstdint>

// NeuralRadiance via bf16 MFMA (16x16x32), register-only inter-layer transforms.
//   L1 (transposed): h1^T = W1^T @ x^T   -- b1 folded as x[k=19]=1.0
//   L2 (transposed): h2^T = W2^T @ h1^T  -- b2 via MFMA C operand
//   L3 (normal)    : h3   = h2  @ W3     -- b3 via MFMA C operand
// Fragment facts (HW-verified per guide):
//   A-frag: lane holds A[m=lane&15][k=quad*8+j], 8 bf16
//   B-frag: lane holds B[k=quad*8+j][n=lane&15], 8 bf16
//   C/D   : lane reg r holds D[m=quad*4+r][n=lane&15], 4 f32
// Round 8:
//  (a) weight prologue eliminated: setup kernel writes fragment-ordered bf16
//      weights to d_ws; main kernel does 14 coalesced L2-broadcast dwordx4
//      loads per lane. r5-r7 evidence: ~4.7k LDS conflict-cycles PER BLOCK
//      were all w2t staging (row stride 64 shorts = single-bank writes) ->
//      ~15us serialized DS per CU at 8 blocks/CU. Also removes both barriers.
//  (b) 2-sub ILP jam: subs share no LDS state since r5, so run them in
//      interleaved pairs -> two independent MFMA/VALU chains per wave
//      (occupancy is register-capped at ~3-4 waves/SIMD; ILP is the lever).

typedef short  bf16x8 __attribute__((ext_vector_type(8)));
typedef float  f32x4  __attribute__((ext_vector_type(4)));

#define MFMA16(A, B, C) __builtin_amdgcn_mfma_f32_16x16x32_bf16((A), (B), (C), 0, 0, 0)

// guaranteed-HW packed cvt: 2 f32 -> dword of 2 bf16 (lo=a, hi=b), RNE
__device__ inline int pk(float a, float b) {
    int d;
    __asm__("v_cvt_pk_bf16_f32 %0, %1, %2" : "=v"(d) : "v"(a), "v"(b));
    return d;
}

// gfx950 lane-transpose primitives (both operands read-write)
__device__ inline void pl32_swap(int& a, int& b) {
    __asm__ volatile("v_permlane32_swap_b32 %0, %1" : "+v"(a), "+v"(b));
}
__device__ inline void pl16_swap(int& a, int& b) {
    __asm__ volatile("v_permlane16_swap_b32 %0, %1" : "+v"(a), "+v"(b));
}

// compile-time ordering only (DS pipe is in-order per wave; validated r4-r7)
__device__ inline void cfence() { __asm__ volatile("" ::: "memory"); }

__device__ inline float sigmoid_fast(float x) {
    float e = __expf(-x);
    return __builtin_amdgcn_rcpf(1.0f + e);
}

// C/D accs (4x f32x4) -> two frag halves (int4 of bf16 pairs), with relu.
__device__ inline void cd_to_frag(const f32x4 acc[4], int4& lo, int4& hi) {
    int P0 = pk(fmaxf(acc[0][0],0.f), fmaxf(acc[0][1],0.f));
    int P1 = pk(fmaxf(acc[0][2],0.f), fmaxf(acc[0][3],0.f));
    int P2 = pk(fmaxf(acc[1][0],0.f), fmaxf(acc[1][1],0.f));
    int P3 = pk(fmaxf(acc[1][2],0.f), fmaxf(acc[1][3],0.f));
    int P4 = pk(fmaxf(acc[2][0],0.f), fmaxf(acc[2][1],0.f));
    int P5 = pk(fmaxf(acc[2][2],0.f), fmaxf(acc[2][3],0.f));
    int P6 = pk(fmaxf(acc[3][0],0.f), fmaxf(acc[3][1],0.f));
    int P7 = pk(fmaxf(acc[3][2],0.f), fmaxf(acc[3][3],0.f));
    pl32_swap(P0, P2); pl16_swap(P0, P2);   // -> T0, T2
    pl32_swap(P1, P3); pl16_swap(P1, P3);   // -> T1, T3
    pl32_swap(P4, P6); pl16_swap(P4, P6);   // -> T4, T6
    pl32_swap(P5, P7); pl16_swap(P5, P7);   // -> T5, T7
    lo = make_int4(P0, P1, P2, P3);
    hi = make_int4(P4, P5, P6, P7);
}

__device__ inline bf16x8 as_frag(int4 v) {
    bf16x8 f; __builtin_memcpy(&f, &v, sizeof(f)); return f;
}

#define XS 40   // xbuf row stride in shorts (20 dwords; b128 at bank floor)

// ---- setup: write fragment-ordered bf16 weights to ws (int4 units):
//   ws[0..255]   : w1 frags  [t*64+lane]       t=0..3
//   ws[256..767] : w2 frags  [(t*2+ks)*64+lane]
//   ws[768..895] : w3 frags  [h*64+lane]       h=0..1
__global__ __launch_bounds__(256) void nrad_setup_kernel(
    const float* __restrict__ W1, const float* __restrict__ b1,
    const float* __restrict__ W2, const float* __restrict__ W3,
    float* __restrict__ ws)
{
    const int tid  = threadIdx.x;
    const int wv   = tid >> 6;
    const int lane = tid & 63;
    const int q    = lane >> 4;
    const int nn   = lane & 15;
    int4* w1o = (int4*)ws;
    int4* w2o = (int4*)ws + 256;
    int4* w3o = (int4*)ws + 768;

    if (wv == 0) {
        // A-frag of W1T tile t: A[m=nn][k=q*8+j], W1T[n][k] = k<19?W1[k*64+n]:(k==19?b1[n]:0)
        for (int t = 0; t < 4; ++t) {
            int n = t * 16 + nn;
            float v[8];
            #pragma unroll
            for (int j = 0; j < 8; ++j) {
                int k = q * 8 + j;
                v[j] = (k < 19) ? W1[k * 64 + n] : (k == 19 ? b1[n] : 0.0f);
            }
            w1o[t * 64 + lane] = make_int4(pk(v[0],v[1]), pk(v[2],v[3]),
                                           pk(v[4],v[5]), pk(v[6],v[7]));
        }
    } else if (wv == 3) {
        // B-frag of W3 (64x3 zero-padded to 64x16): B[k=h*32+q*8+j][n=nn]
        for (int h = 0; h < 2; ++h) {
            float v[8];
            #pragma unroll
            for (int j = 0; j < 8; ++j) {
                int k = h * 32 + q * 8 + j;
                v[j] = (nn < 3) ? W3[k * 3 + nn] : 0.0f;
            }
            w3o[h * 64 + lane] = make_int4(pk(v[0],v[1]), pk(v[2],v[3]),
                                           pk(v[4],v[5]), pk(v[6],v[7]));
        }
    } else {
        // A-frag of W2T tile (t,ks): A[m=nn][k=ks*32+q*8+j] = W2[k*64 + t*16+nn]
        for (int tt = 0; tt < 2; ++tt) {
            int t = (wv - 1) * 2 + tt;
            int n = t * 16 + nn;
            for (int ks = 0; ks < 2; ++ks) {
                float v[8];
                #pragma unroll
                for (int j = 0; j < 8; ++j) {
                    int k = ks * 32 + q * 8 + j;
                    v[j] = W2[k * 64 + n];
                }
                w2o[(t * 2 + ks) * 64 + lane] = make_int4(pk(v[0],v[1]), pk(v[2],v[3]),
                                                          pk(v[4],v[5]), pk(v[6],v[7]));
            }
        }
    }
}

__global__ __launch_bounds__(256, 3) void nrad_mfma_kernel(
    const float* __restrict__ pos, const float* __restrict__ nrm,
    const float* __restrict__ emb,
    const float* __restrict__ b2, const float* __restrict__ b3,
    const float* __restrict__ ws, float* __restrict__ out, int ntiles)
{
    __shared__ alignas(16) short xbuf[4][64 * XS];   // per-wave staging only

    const int tid  = threadIdx.x;
    const int wave = tid >> 6;
    const int lane = tid & 63;
    const int q    = lane >> 4;
    const int nn   = lane & 15;

    // ---- fragment loads: coalesced dwordx4, identical across blocks (L2 broadcast)
    const int4* wsf = (const int4*)ws;
    bf16x8 w1f[4], w2f[4][2], w3f[2];
    #pragma unroll
    for (int t = 0; t < 4; ++t) w1f[t] = as_frag(wsf[t * 64 + lane]);
    #pragma unroll
    for (int t = 0; t < 4; ++t)
        #pragma unroll
        for (int ks = 0; ks < 2; ++ks)
            w2f[t][ks] = as_frag(wsf[256 + (t * 2 + ks) * 64 + lane]);
    w3f[0] = as_frag(wsf[768 + lane]);
    w3f[1] = as_frag(wsf[832 + lane]);
    f32x4 b2rv[4];
    #pragma unroll
    for (int t = 0; t < 4; ++t) b2rv[t] = *(const f32x4*)(b2 + t * 16 + q * 4);
    const float b3r = (nn < 3) ? b3[nn] : 0.0f;

    short* xw = &xbuf[wave][0];
    const int xro  = nn * XS + q * 8;    // + sub*16*XS : L1 B-frag read
    const int oofs = q * 12 + nn;        // out: (q*4+r)*3+nn, r via stride 3

    const int wave_gid = blockIdx.x * 4 + wave;
    const int nwaves   = gridDim.x * 4;
    const float4* emb4 = (const float4*)emb;

    for (int tile = wave_gid; tile < ntiles; tile += nwaves) {
        const int base = tile * 64;
        const int i    = base + lane;

        // ---- load + hash + gather this lane's point
        const float* pp = pos + 3 * i;
        const float* np = nrm + 3 * i;
        float p0 = pp[0], p1 = pp[1], p2 = pp[2];
        float n0 = np[0], n1 = np[1], n2 = np[2];
        int s0 = (int)(p0 * 8.0f), s1 = (int)(p1 * 8.0f), s2 = (int)(p2 * 8.0f);
        uint32_t h = ((uint32_t)s0 * 73856093u) ^ ((uint32_t)s1 * 19349663u) ^
                     ((uint32_t)s2 * 83492791u);
        uint32_t idx = h & 32767u;
        float4 f0 = emb4[idx*4+0], f1 = emb4[idx*4+1];
        float4 f2 = emb4[idx*4+2], f3 = emb4[idx*4+3];

        // ---- pack into xbuf row = lane (k-major, 32 shorts + 8 pad)
        int4 A = make_int4(pk(f0.x, f0.y), pk(f0.z, f0.w), pk(f1.x, f1.y), pk(f1.z, f1.w));
        int4 B = make_int4(pk(f2.x, f2.y), pk(f2.z, f2.w), pk(f3.x, f3.y), pk(f3.z, f3.w));
        int4 C = make_int4(pk(n0, n1), pk(n2, 1.0f), 0, 0);  // k=19 -> 1.0 (bias row)
        int4 D = make_int4(0, 0, 0, 0);
        int4* xr = (int4*)(xw + lane * XS);
        xr[0] = A; xr[1] = B; xr[2] = C; xr[3] = D;
        cfence();

        const float* ob = out + (size_t)base * 3;
        const f32x4 z = {0.0f, 0.0f, 0.0f, 0.0f};

        // ---- 2-sub ILP jam: subs (2sp, 2sp+1) carry independent chains
        #pragma unroll
        for (int sp = 0; sp < 2; ++sp) {
            bf16x8 xfA = *(const bf16x8*)(xw + (2*sp)     * 16 * XS + xro);
            bf16x8 xfB = *(const bf16x8*)(xw + (2*sp + 1) * 16 * XS + xro);

            f32x4 a1A[4], a1B[4];
            #pragma unroll
            for (int t = 0; t < 4; ++t) a1A[t] = MFMA16(w1f[t], xfA, z);
            #pragma unroll
            for (int t = 0; t < 4; ++t) a1B[t] = MFMA16(w1f[t], xfB, z);

            int4 lA, hA, lB, hB;
            cd_to_frag(a1A, lA, hA);
            cd_to_frag(a1B, lB, hB);
            bf16x8 h1A0 = as_frag(lA), h1A1 = as_frag(hA);
            bf16x8 h1B0 = as_frag(lB), h1B1 = as_frag(hB);

            f32x4 a2A[4], a2B[4];
            #pragma unroll
            for (int t = 0; t < 4; ++t) {
                f32x4 c = MFMA16(w2f[t][0], h1A0, b2rv[t]);
                a2A[t]  = MFMA16(w2f[t][1], h1A1, c);
            }
            #pragma unroll
            for (int t = 0; t < 4; ++t) {
                f32x4 c = MFMA16(w2f[t][0], h1B0, b2rv[t]);
                a2B[t]  = MFMA16(w2f[t][1], h1B1, c);
            }

            cd_to_frag(a2A, lA, hA);
            cd_to_frag(a2B, lB, hB);
            bf16x8 h2A0 = as_frag(lA), h2A1 = as_frag(hA);
            bf16x8 h2B0 = as_frag(lB), h2B1 = as_frag(hB);

            f32x4 cb = {b3r, b3r, b3r, b3r};
            f32x4 acc3A = MFMA16(h2A1, w3f[1], MFMA16(h2A0, w3f[0], cb));
            f32x4 acc3B = MFMA16(h2B1, w3f[1], MFMA16(h2B0, w3f[0], cb));

            float oA0 = sigmoid_fast(acc3A[0]), oA1 = sigmoid_fast(acc3A[1]);
            float oA2 = sigmoid_fast(acc3A[2]), oA3 = sigmoid_fast(acc3A[3]);
            float oB0 = sigmoid_fast(acc3B[0]), oB1 = sigmoid_fast(acc3B[1]);
            float oB2 = sigmoid_fast(acc3B[2]), oB3 = sigmoid_fast(acc3B[3]);
            if (nn < 3) {
                float* oa = (float*)(ob + (2*sp)     * 48 + oofs);
                float* obp= (float*)(ob + (2*sp + 1) * 48 + oofs);
                oa[0] = oA0; oa[3] = oA1; oa[6] = oA2; oa[9] = oA3;
                obp[0] = oB0; obp[3] = oB1; obp[6] = oB2; obp[9] = oB3;
            }
        }
        cfence();   // next tile's xbuf writes stay behind this tile's reads
    }
}

extern "C" void kernel_launch(void* const* d_in, const int* in_sizes, int n_in,
                              void* d_out, int out_size, void* d_ws, size_t ws_size,
                              hipStream_t stream) {
    const float* pos = (const float*)d_in[0];
    const float* nrm = (const float*)d_in[1];
    const float* emb = (const float*)d_in[2];
    const float* W1  = (const float*)d_in[3];
    const float* b1  = (const float*)d_in[4];
    const float* W2  = (const float*)d_in[5];
    const float* b2  = (const float*)d_in[6];
    const float* W3  = (const float*)d_in[7];
    const float* b3  = (const float*)d_in[8];
    float* out = (float*)d_out;
    float* ws  = (float*)d_ws;   // 896 int4 = 14336 B used

    int n = in_sizes[0] / 3;      // 2,097,152
    int ntiles = n / 64;          // 32768

    nrad_setup_kernel<<<1, 256, 0, stream>>>(W1, b1, W2, W3, ws);
    nrad_mfma_kernel<<<2048, 256, 0, stream>>>(pos, nrm, emb, b2, b3, ws,
                                               out, ntiles);
}

// Round 9
// 144.620 us; speedup vs baseline: 2.6007x; 1.0295x over previous
//
#include <hip/hip_runtime.h>
#include <cstdint>

// NeuralRadiance via bf16 MFMA (16x16x32), register-only inter-layer transforms.
//   L1 (transposed): h1^T = W1^T @ x^T   -- b1 folded as x[k=19]=1.0
//   L2 (transposed): h2^T = W2^T @ h1^T  -- b2 via MFMA C operand
//   L3 (normal)    : h3   = h2  @ W3     -- b3 via MFMA C operand
// Fragment facts (HW-verified per guide):
//   A-frag: lane holds A[m=lane&15][k=quad*8+j], 8 bf16
//   B-frag: lane holds B[k=quad*8+j][n=lane&15], 8 bf16
//   C/D   : lane reg r holds D[m=quad*4+r][n=lane&15], 4 f32
// Round 9: register diet. r5-r8 evidence: throughput is resident-wave
// bound (per-wave tile wall ~13k cyc vs ~1.1k issue cyc) and residency is
// register-capped (occ 25% at jam). W2's 8 fragments (32 VGPRs, read-only)
// move to LDS ([frag][lane] int4, conflict-free canonical pattern), re-read
// per sub-pair with 8 ds_read_b128. Single change vs r8.

typedef short  bf16x8 __attribute__((ext_vector_type(8)));
typedef float  f32x4  __attribute__((ext_vector_type(4)));

#define MFMA16(A, B, C) __builtin_amdgcn_mfma_f32_16x16x32_bf16((A), (B), (C), 0, 0, 0)

// guaranteed-HW packed cvt: 2 f32 -> dword of 2 bf16 (lo=a, hi=b), RNE
__device__ inline int pk(float a, float b) {
    int d;
    __asm__("v_cvt_pk_bf16_f32 %0, %1, %2" : "=v"(d) : "v"(a), "v"(b));
    return d;
}

// gfx950 lane-transpose primitives (both operands read-write)
__device__ inline void pl32_swap(int& a, int& b) {
    __asm__ volatile("v_permlane32_swap_b32 %0, %1" : "+v"(a), "+v"(b));
}
__device__ inline void pl16_swap(int& a, int& b) {
    __asm__ volatile("v_permlane16_swap_b32 %0, %1" : "+v"(a), "+v"(b));
}

// compile-time ordering only (DS pipe is in-order per wave; validated r4-r8)
__device__ inline void cfence() { __asm__ volatile("" ::: "memory"); }

__device__ inline float sigmoid_fast(float x) {
    float e = __expf(-x);
    return __builtin_amdgcn_rcpf(1.0f + e);
}

// C/D accs (4x f32x4) -> two frag halves (int4 of bf16 pairs), with relu.
__device__ inline void cd_to_frag(const f32x4 acc[4], int4& lo, int4& hi) {
    int P0 = pk(fmaxf(acc[0][0],0.f), fmaxf(acc[0][1],0.f));
    int P1 = pk(fmaxf(acc[0][2],0.f), fmaxf(acc[0][3],0.f));
    int P2 = pk(fmaxf(acc[1][0],0.f), fmaxf(acc[1][1],0.f));
    int P3 = pk(fmaxf(acc[1][2],0.f), fmaxf(acc[1][3],0.f));
    int P4 = pk(fmaxf(acc[2][0],0.f), fmaxf(acc[2][1],0.f));
    int P5 = pk(fmaxf(acc[2][2],0.f), fmaxf(acc[2][3],0.f));
    int P6 = pk(fmaxf(acc[3][0],0.f), fmaxf(acc[3][1],0.f));
    int P7 = pk(fmaxf(acc[3][2],0.f), fmaxf(acc[3][3],0.f));
    pl32_swap(P0, P2); pl16_swap(P0, P2);   // -> T0, T2
    pl32_swap(P1, P3); pl16_swap(P1, P3);   // -> T1, T3
    pl32_swap(P4, P6); pl16_swap(P4, P6);   // -> T4, T6
    pl32_swap(P5, P7); pl16_swap(P5, P7);   // -> T5, T7
    lo = make_int4(P0, P1, P2, P3);
    hi = make_int4(P4, P5, P6, P7);
}

__device__ inline bf16x8 as_frag(int4 v) {
    bf16x8 f; __builtin_memcpy(&f, &v, sizeof(f)); return f;
}

#define XS 40   // xbuf row stride in shorts (20 dwords; b128 at bank floor)

// ---- setup: write fragment-ordered bf16 weights to ws (int4 units):
//   ws[0..255]   : w1 frags  [t*64+lane]       t=0..3
//   ws[256..767] : w2 frags  [(t*2+ks)*64+lane]
//   ws[768..895] : w3 frags  [h*64+lane]       h=0..1
__global__ __launch_bounds__(256) void nrad_setup_kernel(
    const float* __restrict__ W1, const float* __restrict__ b1,
    const float* __restrict__ W2, const float* __restrict__ W3,
    float* __restrict__ ws)
{
    const int tid  = threadIdx.x;
    const int wv   = tid >> 6;
    const int lane = tid & 63;
    const int q    = lane >> 4;
    const int nn   = lane & 15;
    int4* w1o = (int4*)ws;
    int4* w2o = (int4*)ws + 256;
    int4* w3o = (int4*)ws + 768;

    if (wv == 0) {
        // A-frag of W1T tile t: A[m=nn][k=q*8+j], W1T[n][k] = k<19?W1[k*64+n]:(k==19?b1[n]:0)
        for (int t = 0; t < 4; ++t) {
            int n = t * 16 + nn;
            float v[8];
            #pragma unroll
            for (int j = 0; j < 8; ++j) {
                int k = q * 8 + j;
                v[j] = (k < 19) ? W1[k * 64 + n] : (k == 19 ? b1[n] : 0.0f);
            }
            w1o[t * 64 + lane] = make_int4(pk(v[0],v[1]), pk(v[2],v[3]),
                                           pk(v[4],v[5]), pk(v[6],v[7]));
        }
    } else if (wv == 3) {
        // B-frag of W3 (64x3 zero-padded to 64x16): B[k=h*32+q*8+j][n=nn]
        for (int h = 0; h < 2; ++h) {
            float v[8];
            #pragma unroll
            for (int j = 0; j < 8; ++j) {
                int k = h * 32 + q * 8 + j;
                v[j] = (nn < 3) ? W3[k * 3 + nn] : 0.0f;
            }
            w3o[h * 64 + lane] = make_int4(pk(v[0],v[1]), pk(v[2],v[3]),
                                           pk(v[4],v[5]), pk(v[6],v[7]));
        }
    } else {
        // A-frag of W2T tile (t,ks): A[m=nn][k=ks*32+q*8+j] = W2[k*64 + t*16+nn]
        for (int tt = 0; tt < 2; ++tt) {
            int t = (wv - 1) * 2 + tt;
            int n = t * 16 + nn;
            for (int ks = 0; ks < 2; ++ks) {
                float v[8];
                #pragma unroll
                for (int j = 0; j < 8; ++j) {
                    int k = ks * 32 + q * 8 + j;
                    v[j] = W2[k * 64 + n];
                }
                w2o[(t * 2 + ks) * 64 + lane] = make_int4(pk(v[0],v[1]), pk(v[2],v[3]),
                                                          pk(v[4],v[5]), pk(v[6],v[7]));
            }
        }
    }
}

__global__ __launch_bounds__(256, 3) void nrad_mfma_kernel(
    const float* __restrict__ pos, const float* __restrict__ nrm,
    const float* __restrict__ emb,
    const float* __restrict__ b2, const float* __restrict__ b3,
    const float* __restrict__ ws, float* __restrict__ out, int ntiles)
{
    // w2lds: 8 frags x 64 lanes x 16B = 8 KB, [frag][lane] (conflict-free);
    // xbuf : per-wave x staging (4 x 5120 B).
    __shared__ alignas(16) int4  w2lds[512];
    __shared__ alignas(16) short xbuf[4][64 * XS];

    const int tid  = threadIdx.x;
    const int wave = tid >> 6;
    const int lane = tid & 63;
    const int q    = lane >> 4;
    const int nn   = lane & 15;

    // ---- stage W2 fragments into LDS (coalesced read, canonical write)
    const int4* wsf = (const int4*)ws;
    w2lds[tid]       = wsf[256 + tid];
    w2lds[tid + 256] = wsf[512 + tid];
    __syncthreads();

    // ---- register fragments: w1, w3 only (w2 stays in LDS)
    bf16x8 w1f[4], w3f[2];
    #pragma unroll
    for (int t = 0; t < 4; ++t) w1f[t] = as_frag(wsf[t * 64 + lane]);
    w3f[0] = as_frag(wsf[768 + lane]);
    w3f[1] = as_frag(wsf[832 + lane]);
    f32x4 b2rv[4];
    #pragma unroll
    for (int t = 0; t < 4; ++t) b2rv[t] = *(const f32x4*)(b2 + t * 16 + q * 4);
    const float b3r = (nn < 3) ? b3[nn] : 0.0f;

    short* xw = &xbuf[wave][0];
    const int4* w2l = w2lds + lane;      // + (t*2+ks)*64
    const int xro  = nn * XS + q * 8;    // + sub*16*XS : L1 B-frag read
    const int oofs = q * 12 + nn;        // out: (q*4+r)*3+nn, r via stride 3

    const int wave_gid = blockIdx.x * 4 + wave;
    const int nwaves   = gridDim.x * 4;
    const float4* emb4 = (const float4*)emb;

    for (int tile = wave_gid; tile < ntiles; tile += nwaves) {
        const int base = tile * 64;
        const int i    = base + lane;

        // ---- load + hash + gather this lane's point
        const float* pp = pos + 3 * i;
        const float* np = nrm + 3 * i;
        float p0 = pp[0], p1 = pp[1], p2 = pp[2];
        float n0 = np[0], n1 = np[1], n2 = np[2];
        int s0 = (int)(p0 * 8.0f), s1 = (int)(p1 * 8.0f), s2 = (int)(p2 * 8.0f);
        uint32_t h = ((uint32_t)s0 * 73856093u) ^ ((uint32_t)s1 * 19349663u) ^
                     ((uint32_t)s2 * 83492791u);
        uint32_t idx = h & 32767u;
        float4 f0 = emb4[idx*4+0], f1 = emb4[idx*4+1];
        float4 f2 = emb4[idx*4+2], f3 = emb4[idx*4+3];

        // ---- pack into xbuf row = lane (k-major, 32 shorts + 8 pad)
        int4 A = make_int4(pk(f0.x, f0.y), pk(f0.z, f0.w), pk(f1.x, f1.y), pk(f1.z, f1.w));
        int4 B = make_int4(pk(f2.x, f2.y), pk(f2.z, f2.w), pk(f3.x, f3.y), pk(f3.z, f3.w));
        int4 C = make_int4(pk(n0, n1), pk(n2, 1.0f), 0, 0);  // k=19 -> 1.0 (bias row)
        int4 D = make_int4(0, 0, 0, 0);
        int4* xr = (int4*)(xw + lane * XS);
        xr[0] = A; xr[1] = B; xr[2] = C; xr[3] = D;
        cfence();

        const float* ob = out + (size_t)base * 3;
        const f32x4 z = {0.0f, 0.0f, 0.0f, 0.0f};

        // ---- 2-sub ILP jam: subs (2sp, 2sp+1) carry independent chains
        #pragma unroll
        for (int sp = 0; sp < 2; ++sp) {
            bf16x8 xfA = *(const bf16x8*)(xw + (2*sp)     * 16 * XS + xro);
            bf16x8 xfB = *(const bf16x8*)(xw + (2*sp + 1) * 16 * XS + xro);

            f32x4 a1A[4], a1B[4];
            #pragma unroll
            for (int t = 0; t < 4; ++t) a1A[t] = MFMA16(w1f[t], xfA, z);
            #pragma unroll
            for (int t = 0; t < 4; ++t) a1B[t] = MFMA16(w1f[t], xfB, z);

            int4 lA, hA, lB, hB;
            cd_to_frag(a1A, lA, hA);
            cd_to_frag(a1B, lB, hB);
            bf16x8 h1A0 = as_frag(lA), h1A1 = as_frag(hA);
            bf16x8 h1B0 = as_frag(lB), h1B1 = as_frag(hB);

            // ---- L2 with W2 frags streamed from LDS (per-lane b128 reads)
            f32x4 a2A[4], a2B[4];
            #pragma unroll
            for (int t = 0; t < 4; ++t) {
                bf16x8 w20 = as_frag(w2l[(t * 2 + 0) * 64]);
                bf16x8 w21 = as_frag(w2l[(t * 2 + 1) * 64]);
                f32x4 cA = MFMA16(w20, h1A0, b2rv[t]);
                a2A[t]   = MFMA16(w21, h1A1, cA);
                f32x4 cB = MFMA16(w20, h1B0, b2rv[t]);
                a2B[t]   = MFMA16(w21, h1B1, cB);
            }

            cd_to_frag(a2A, lA, hA);
            cd_to_frag(a2B, lB, hB);
            bf16x8 h2A0 = as_frag(lA), h2A1 = as_frag(hA);
            bf16x8 h2B0 = as_frag(lB), h2B1 = as_frag(hB);

            f32x4 cb = {b3r, b3r, b3r, b3r};
            f32x4 acc3A = MFMA16(h2A1, w3f[1], MFMA16(h2A0, w3f[0], cb));
            f32x4 acc3B = MFMA16(h2B1, w3f[1], MFMA16(h2B0, w3f[0], cb));

            float oA0 = sigmoid_fast(acc3A[0]), oA1 = sigmoid_fast(acc3A[1]);
            float oA2 = sigmoid_fast(acc3A[2]), oA3 = sigmoid_fast(acc3A[3]);
            float oB0 = sigmoid_fast(acc3B[0]), oB1 = sigmoid_fast(acc3B[1]);
            float oB2 = sigmoid_fast(acc3B[2]), oB3 = sigmoid_fast(acc3B[3]);
            if (nn < 3) {
                float* oa = (float*)(ob + (2*sp)     * 48 + oofs);
                float* obp= (float*)(ob + (2*sp + 1) * 48 + oofs);
                oa[0] = oA0; oa[3] = oA1; oa[6] = oA2; oa[9] = oA3;
                obp[0] = oB0; obp[3] = oB1; obp[6] = oB2; obp[9] = oB3;
            }
        }
        cfence();   // next tile's xbuf writes stay behind this tile's reads
    }
}

extern "C" void kernel_launch(void* const* d_in, const int* in_sizes, int n_in,
                              void* d_out, int out_size, void* d_ws, size_t ws_size,
                              hipStream_t stream) {
    const float* pos = (const float*)d_in[0];
    const float* nrm = (const float*)d_in[1];
    const float* emb = (const float*)d_in[2];
    const float* W1  = (const float*)d_in[3];
    const float* b1  = (const float*)d_in[4];
    const float* W2  = (const float*)d_in[5];
    const float* b2  = (const float*)d_in[6];
    const float* W3  = (const float*)d_in[7];
    const float* b3  = (const float*)d_in[8];
    float* out = (float*)d_out;
    float* ws  = (float*)d_ws;   // 896 int4 = 14336 B used

    int n = in_sizes[0] / 3;      // 2,097,152
    int ntiles = n / 64;          // 32768

    nrad_setup_kernel<<<1, 256, 0, stream>>>(W1, b1, W2, W3, ws);
    nrad_mfma_kernel<<<2048, 256, 0, stream>>>(pos, nrm, emb, b2, b3, ws,
                                               out, ntiles);
}

// Round 10
// 142.138 us; speedup vs baseline: 2.6461x; 1.0175x over previous
//
#include <hip/hip_runtime.h>
#include <cstdint>

// NeuralRadiance via bf16 MFMA (16x16x32). Round 10:
//  (a) PERMLANE-FREE inter-layer transform. The packed D-regs of a layer,
//      read as the next layer's A/B-frag, present logical feature
//      Lam(k) = 32*(k>>5) + 16*((k>>2)&1) + 4*((k>>3)&3) + (k&3)
//      at k-position k (bijection: swaps the q and tile-parity fields).
//      Feature order inside hidden layers is arbitrary, so the setup kernel
//      pre-permutes W2's and W3's input rows by Lam, and relu+pack of D
//      registers IS the next fragment. Kills 64 serialized permlanes/tile.
//  (b) staged prefetch: next tile's pos/nrm issued before sub-pair 0,
//      hash+emb gather between pairs, consumed at next loop top -- hides the
//      ~1400-cyc global chain under compute. (cap 170 via (256,3); FETCH is
//      the spill tripwire.)
// Layout facts (HW-verified): A-frag lane holds A[m=lane&15][k=quad*8+j];
// B-frag B[k=quad*8+j][n=lane&15]; C/D reg r = D[m=quad*4+r][n=lane&15].

typedef short  bf16x8 __attribute__((ext_vector_type(8)));
typedef float  f32x4  __attribute__((ext_vector_type(4)));

#define MFMA16(A, B, C) __builtin_amdgcn_mfma_f32_16x16x32_bf16((A), (B), (C), 0, 0, 0)

// guaranteed-HW packed cvt: 2 f32 -> dword of 2 bf16 (lo=a, hi=b), RNE
__device__ inline int pk(float a, float b) {
    int d;
    __asm__("v_cvt_pk_bf16_f32 %0, %1, %2" : "=v"(d) : "v"(a), "v"(b));
    return d;
}

// compile-time ordering only (DS pipe is in-order per wave; validated r4-r9)
__device__ inline void cfence() { __asm__ volatile("" ::: "memory"); }

__device__ inline float sigmoid_fast(float x) {
    float e = __expf(-x);
    return __builtin_amdgcn_rcpf(1.0f + e);
}

// logical feature held at k-position k of the packed-D fragment
__device__ inline int lam(int k) {
    return 32 * (k >> 5) + 16 * ((k >> 2) & 1) + 4 * ((k >> 3) & 3) + (k & 3);
}

// C/D accs (4x f32x4) -> next-layer frag halves: relu + pack ONLY.
__device__ inline void cd_pack(const f32x4 acc[4], int4& lo, int4& hi) {
    lo = make_int4(pk(fmaxf(acc[0][0],0.f), fmaxf(acc[0][1],0.f)),
                   pk(fmaxf(acc[0][2],0.f), fmaxf(acc[0][3],0.f)),
                   pk(fmaxf(acc[1][0],0.f), fmaxf(acc[1][1],0.f)),
                   pk(fmaxf(acc[1][2],0.f), fmaxf(acc[1][3],0.f)));
    hi = make_int4(pk(fmaxf(acc[2][0],0.f), fmaxf(acc[2][1],0.f)),
                   pk(fmaxf(acc[2][2],0.f), fmaxf(acc[2][3],0.f)),
                   pk(fmaxf(acc[3][0],0.f), fmaxf(acc[3][1],0.f)),
                   pk(fmaxf(acc[3][2],0.f), fmaxf(acc[3][3],0.f)));
}

__device__ inline bf16x8 as_frag(int4 v) {
    bf16x8 f; __builtin_memcpy(&f, &v, sizeof(f)); return f;
}

#define XS 40   // xbuf row stride in shorts (20 dwords; b128 at bank floor)

// ---- setup: fragment-ordered bf16 weights in ws (int4 units):
//   ws[0..255]   : w1 frags [t*64+lane]          (identity out-feats)
//   ws[256..767] : w2 frags [(t*2+ks)*64+lane]   (input rows permuted by lam)
//   ws[768..895] : w3 frags [h*64+lane]          (input rows permuted by lam)
__global__ __launch_bounds__(256) void nrad_setup_kernel(
    const float* __restrict__ W1, const float* __restrict__ b1,
    const float* __restrict__ W2, const float* __restrict__ W3,
    float* __restrict__ ws)
{
    const int tid  = threadIdx.x;
    const int wv   = tid >> 6;
    const int lane = tid & 63;
    const int q    = lane >> 4;
    const int nn   = lane & 15;
    int4* w1o = (int4*)ws;
    int4* w2o = (int4*)ws + 256;
    int4* w3o = (int4*)ws + 768;

    if (wv == 0) {
        // A-frag of W1T tile t: A[m=nn][k=q*8+j]; k<19=W1, k==19=b1, else 0
        for (int t = 0; t < 4; ++t) {
            int n = t * 16 + nn;
            float v[8];
            #pragma unroll
            for (int j = 0; j < 8; ++j) {
                int k = q * 8 + j;
                v[j] = (k < 19) ? W1[k * 64 + n] : (k == 19 ? b1[n] : 0.0f);
            }
            w1o[t * 64 + lane] = make_int4(pk(v[0],v[1]), pk(v[2],v[3]),
                                           pk(v[4],v[5]), pk(v[6],v[7]));
        }
    } else if (wv == 3) {
        // B-frag of W3 (rows permuted by lam; cols zero-padded past 3)
        for (int h = 0; h < 2; ++h) {
            float v[8];
            #pragma unroll
            for (int j = 0; j < 8; ++j) {
                int kin = lam(h * 32 + q * 8 + j);
                v[j] = (nn < 3) ? W3[kin * 3 + nn] : 0.0f;
            }
            w3o[h * 64 + lane] = make_int4(pk(v[0],v[1]), pk(v[2],v[3]),
                                           pk(v[4],v[5]), pk(v[6],v[7]));
        }
    } else {
        // A-frag of W2T tile (t,ks): A[m=nn][k] = W2[lam(k)][t*16+nn]
        for (int tt = 0; tt < 2; ++tt) {
            int t = (wv - 1) * 2 + tt;
            int n = t * 16 + nn;
            for (int ks = 0; ks < 2; ++ks) {
                float v[8];
                #pragma unroll
                for (int j = 0; j < 8; ++j) {
                    int kin = lam(ks * 32 + q * 8 + j);
                    v[j] = W2[kin * 64 + n];
                }
                w2o[(t * 2 + ks) * 64 + lane] = make_int4(pk(v[0],v[1]), pk(v[2],v[3]),
                                                          pk(v[4],v[5]), pk(v[6],v[7]));
            }
        }
    }
}

__global__ __launch_bounds__(256, 3) void nrad_mfma_kernel(
    const float* __restrict__ pos, const float* __restrict__ nrm,
    const float* __restrict__ emb,
    const float* __restrict__ b2, const float* __restrict__ b3,
    const float* __restrict__ ws, float* __restrict__ out, int ntiles)
{
    // w2lds: 8 frags x 64 lanes x 16B = 8KB [frag][lane] (conflict-free);
    // xbuf : per-wave x staging.
    __shared__ alignas(16) int4  w2lds[512];
    __shared__ alignas(16) short xbuf[4][64 * XS];

    const int tid  = threadIdx.x;
    const int wave = tid >> 6;
    const int lane = tid & 63;
    const int q    = lane >> 4;
    const int nn   = lane & 15;

    // ---- stage W2 fragments into LDS
    const int4* wsf = (const int4*)ws;
    w2lds[tid]       = wsf[256 + tid];
    w2lds[tid + 256] = wsf[512 + tid];
    __syncthreads();

    // ---- register fragments: w1, w3 (w2 streams from LDS)
    bf16x8 w1f[4], w3f[2];
    #pragma unroll
    for (int t = 0; t < 4; ++t) w1f[t] = as_frag(wsf[t * 64 + lane]);
    w3f[0] = as_frag(wsf[768 + lane]);
    w3f[1] = as_frag(wsf[832 + lane]);
    f32x4 b2rv[4];
    #pragma unroll
    for (int t = 0; t < 4; ++t) b2rv[t] = *(const f32x4*)(b2 + t * 16 + q * 4);
    const float b3r = (nn < 3) ? b3[nn] : 0.0f;

    short* xw = &xbuf[wave][0];
    const int4* w2l = w2lds + lane;      // + (t*2+ks)*64
    const int xro  = nn * XS + q * 8;    // + sub*16*XS : L1 B-frag read
    const int oofs = q * 12 + nn;        // out: (q*4+r)*3+nn, r via stride 3

    const int wave_gid = blockIdx.x * 4 + wave;
    const int nwaves   = gridDim.x * 4;
    const float4* emb4 = (const float4*)emb;

    // ---- prefetch state (loop-carried): normal + gathered embedding
    float n0 = 0, n1 = 0, n2 = 0;
    float4 f0{}, f1{}, f2{}, f3{};
    if (wave_gid < ntiles) {
        int i = wave_gid * 64 + lane;
        float p0 = pos[3*i], p1 = pos[3*i+1], p2 = pos[3*i+2];
        n0 = nrm[3*i]; n1 = nrm[3*i+1]; n2 = nrm[3*i+2];
        int s0 = (int)(p0 * 8.0f), s1 = (int)(p1 * 8.0f), s2 = (int)(p2 * 8.0f);
        uint32_t h = ((uint32_t)s0 * 73856093u) ^ ((uint32_t)s1 * 19349663u) ^
                     ((uint32_t)s2 * 83492791u);
        uint32_t idx = h & 32767u;
        f0 = emb4[idx*4+0]; f1 = emb4[idx*4+1];
        f2 = emb4[idx*4+2]; f3 = emb4[idx*4+3];
    }

    for (int tile = wave_gid; tile < ntiles; tile += nwaves) {
        const int base = tile * 64;
        const float* ob = out + (size_t)base * 3;
        const f32x4 z = {0.0f, 0.0f, 0.0f, 0.0f};

        // ---- pack prefetched point into xbuf row = lane
        {
            int4 A = make_int4(pk(f0.x, f0.y), pk(f0.z, f0.w), pk(f1.x, f1.y), pk(f1.z, f1.w));
            int4 B = make_int4(pk(f2.x, f2.y), pk(f2.z, f2.w), pk(f3.x, f3.y), pk(f3.z, f3.w));
            int4 C = make_int4(pk(n0, n1), pk(n2, 1.0f), 0, 0);  // k=19 -> 1.0 (bias)
            int4 D = make_int4(0, 0, 0, 0);
            int4* xr = (int4*)(xw + lane * XS);
            xr[0] = A; xr[1] = B; xr[2] = C; xr[3] = D;
        }
        cfence();

        // ---- stage A: issue next tile's pos/nrm loads (consumed at stage B / next top)
        int nt = tile + nwaves;
        int lt = (nt < ntiles) ? nt : tile;   // wave-uniform clamp
        int inext = lt * 64 + lane;
        float q0 = pos[3*inext], q1 = pos[3*inext+1], q2 = pos[3*inext+2];
        n0 = nrm[3*inext]; n1 = nrm[3*inext+1]; n2 = nrm[3*inext+2];

        // ---- one jammed sub-pair (subs 2sp, 2sp+1): two independent chains
        auto do_pair = [&](int sp) {
            bf16x8 xfA = *(const bf16x8*)(xw + (2*sp)     * 16 * XS + xro);
            bf16x8 xfB = *(const bf16x8*)(xw + (2*sp + 1) * 16 * XS + xro);

            f32x4 a1A[4], a1B[4];
            #pragma unroll
            for (int t = 0; t < 4; ++t) a1A[t] = MFMA16(w1f[t], xfA, z);
            #pragma unroll
            for (int t = 0; t < 4; ++t) a1B[t] = MFMA16(w1f[t], xfB, z);

            int4 lA, hA, lB, hB;
            cd_pack(a1A, lA, hA);
            cd_pack(a1B, lB, hB);
            bf16x8 h1A0 = as_frag(lA), h1A1 = as_frag(hA);
            bf16x8 h1B0 = as_frag(lB), h1B1 = as_frag(hB);

            f32x4 a2A[4], a2B[4];
            #pragma unroll
            for (int t = 0; t < 4; ++t) {
                bf16x8 w20 = as_frag(w2l[(t * 2 + 0) * 64]);
                bf16x8 w21 = as_frag(w2l[(t * 2 + 1) * 64]);
                f32x4 cA = MFMA16(w20, h1A0, b2rv[t]);
                a2A[t]   = MFMA16(w21, h1A1, cA);
                f32x4 cB = MFMA16(w20, h1B0, b2rv[t]);
                a2B[t]   = MFMA16(w21, h1B1, cB);
            }

            cd_pack(a2A, lA, hA);
            cd_pack(a2B, lB, hB);
            bf16x8 h2A0 = as_frag(lA), h2A1 = as_frag(hA);
            bf16x8 h2B0 = as_frag(lB), h2B1 = as_frag(hB);

            f32x4 cb = {b3r, b3r, b3r, b3r};
            f32x4 acc3A = MFMA16(h2A1, w3f[1], MFMA16(h2A0, w3f[0], cb));
            f32x4 acc3B = MFMA16(h2B1, w3f[1], MFMA16(h2B0, w3f[0], cb));

            float oA0 = sigmoid_fast(acc3A[0]), oA1 = sigmoid_fast(acc3A[1]);
            float oA2 = sigmoid_fast(acc3A[2]), oA3 = sigmoid_fast(acc3A[3]);
            float oB0 = sigmoid_fast(acc3B[0]), oB1 = sigmoid_fast(acc3B[1]);
            float oB2 = sigmoid_fast(acc3B[2]), oB3 = sigmoid_fast(acc3B[3]);
            if (nn < 3) {
                float* oa = (float*)(ob + (2*sp)     * 48 + oofs);
                float* obp= (float*)(ob + (2*sp + 1) * 48 + oofs);
                oa[0] = oA0; oa[3] = oA1; oa[6] = oA2; oa[9] = oA3;
                obp[0] = oB0; obp[3] = oB1; obp[6] = oB2; obp[9] = oB3;
            }
        };

        do_pair(0);

        // ---- stage B: hash from prefetched pos (waits pos only), issue emb gather
        {
            int s0 = (int)(q0 * 8.0f), s1 = (int)(q1 * 8.0f), s2 = (int)(q2 * 8.0f);
            uint32_t h = ((uint32_t)s0 * 73856093u) ^ ((uint32_t)s1 * 19349663u) ^
                         ((uint32_t)s2 * 83492791u);
            uint32_t idx = h & 32767u;
            f0 = emb4[idx*4+0]; f1 = emb4[idx*4+1];
            f2 = emb4[idx*4+2]; f3 = emb4[idx*4+3];
        }

        do_pair(1);

        cfence();   // next tile's xbuf writes stay behind this tile's reads
    }
}

extern "C" void kernel_launch(void* const* d_in, const int* in_sizes, int n_in,
                              void* d_out, int out_size, void* d_ws, size_t ws_size,
                              hipStream_t stream) {
    const float* pos = (const float*)d_in[0];
    const float* nrm = (const float*)d_in[1];
    const float* emb = (const float*)d_in[2];
    const float* W1  = (const float*)d_in[3];
    const float* b1  = (const float*)d_in[4];
    const float* W2  = (const float*)d_in[5];
    const float* b2  = (const float*)d_in[6];
    const float* W3  = (const float*)d_in[7];
    const float* b3  = (const float*)d_in[8];
    float* out = (float*)d_out;
    float* ws  = (float*)d_ws;   // 896 int4 = 14336 B used

    int n = in_sizes[0] / 3;      // 2,097,152
    int ntiles = n / 64;          // 32768

    nrad_setup_kernel<<<1, 256, 0, stream>>>(W1, b1, W2, W3, ws);
    nrad_mfma_kernel<<<2048, 256, 0, stream>>>(pos, nrm, emb, b2, b3, ws,
                                               out, ntiles);
}